// Round 1
// baseline (710.113 us; speedup 1.0000x reference)
//
#include <hip/hip_runtime.h>
#include <hip/hip_bf16.h>
#include <hip/hip_fp16.h>

// Problem dims (hard-coded): B=8, S=4096, DIM=1024, M=1024
// Algebraic restructure: attn = x @ (mem·W)^T + (mem·b); softmax; out = probs @ mem
// This round: softmax + context-GEMM fused into one kernel (no probs buffer,
// no LDS staging of L2-resident memT, no per-K-step barriers).
#define KDIM 1024

typedef __attribute__((ext_vector_type(8))) __bf16    bf16x8;
typedef __attribute__((ext_vector_type(4))) __bf16    bf16x4;
typedef __attribute__((ext_vector_type(8))) _Float16  half8;
typedef __attribute__((ext_vector_type(4))) _Float16  half4v;
typedef __attribute__((ext_vector_type(4))) float     f32x4;

// async global->LDS, 16B per lane. LDS base must be wave-uniform; HW adds lane*16.
__device__ __forceinline__ void g2l16(const void* g, void* l) {
  __builtin_amdgcn_global_load_lds(
      (const __attribute__((address_space(1))) unsigned int*)g,
      (__attribute__((address_space(3))) unsigned int*)l, 16, 0, 0);
}

__device__ __forceinline__ void split2(float v, __bf16& h, __bf16& l) {
  h = (__bf16)v;
  l = (__bf16)(v - (float)h);
}

// ---------------------------------------------------------------------------
// split mem into bf16 hi/lo (row-major [m][e], already B^T/A layout for P-GEMM)
__global__ __launch_bounds__(256) void split_mem(
    const float* __restrict__ mem, __bf16* __restrict__ Mh, __bf16* __restrict__ Ml) {
  int i = blockIdx.x * 256 + threadIdx.x;   // 1M threads
  __bf16 h, l;
  split2(mem[i], h, l);
  Mh[i] = h; Ml[i] = l;
}

// transpose W [e][d] -> Wt [d][e], split to bf16 hi/lo (B^T layout for P-GEMM)
__global__ __launch_bounds__(256) void transpose_split_W(
    const float* __restrict__ W, __bf16* __restrict__ Wth, __bf16* __restrict__ Wtl) {
  __shared__ float tl[32][33];
  int bx = blockIdx.x, by = blockIdx.y;
  int tx = threadIdx.x, ty = threadIdx.y;   // (32, 8)
#pragma unroll
  for (int j = 0; j < 4; ++j)
    tl[ty + 8 * j][tx] = W[(by * 32 + ty + 8 * j) * 1024 + bx * 32 + tx];
  __syncthreads();
#pragma unroll
  for (int j = 0; j < 4; ++j) {
    float v = tl[tx][ty + 8 * j];
    __bf16 h, l;
    split2(v, h, l);
    const int idx = (bx * 32 + ty + 8 * j) * 1024 + by * 32 + tx;
    Wth[idx] = h; Wtl[idx] = l;
  }
}

// transpose mem [m][d] -> memT fp16 [d][m] (B^T layout for context GEMM)
__global__ __launch_bounds__(256) void transpose_mem(
    const float* __restrict__ mem, _Float16* __restrict__ memT) {
  __shared__ float tl[32][33];
  int bx = blockIdx.x, by = blockIdx.y;
  int tx = threadIdx.x, ty = threadIdx.y;   // (32, 8)
#pragma unroll
  for (int j = 0; j < 4; ++j)
    tl[ty + 8 * j][tx] = mem[(by * 32 + ty + 8 * j) * 1024 + bx * 32 + tx];
  __syncthreads();
#pragma unroll
  for (int j = 0; j < 4; ++j)
    memT[(bx * 32 + ty + 8 * j) * 1024 + by * 32 + tx] =
        (_Float16)tl[tx][ty + 8 * j];
}

// c[m] = sum_e b[e] * mem[m][e]  (fp32). One wave per row.
__global__ __launch_bounds__(256) void bias_c(
    const float* __restrict__ b, const float* __restrict__ mem,
    float* __restrict__ c) {
  const int wave = threadIdx.x >> 6, lane = threadIdx.x & 63;
  const int row = blockIdx.x * 4 + wave;
  float s = 0.f;
#pragma unroll
  for (int j = 0; j < 16; ++j) {
    const int e = lane + 64 * j;
    s += b[e] * mem[row * 1024 + e];
  }
#pragma unroll
  for (int off = 32; off; off >>= 1) s += __shfl_xor(s, off);
  if (lane == 0) c[row] = s;
}

// ---------------------------------------------------------------------------
// Split-bf16 compensated GEMM, C = A @ B^T (3 MFMA products: hh + hl + lh).
// 128x128 tile, BK=32, 32 KB LDS, 4 waves (known-good m97-ish structure).
// MODE 0 (P-GEMM): A pre-split bf16 hi/lo; epilogue writes C as bf16 hi/lo.
// MODE 1 (big GEMM): A = x fp32 (split inline during staging); epilogue adds
//                    bias[col] and writes fp32.
template <int MODE>
__global__ __launch_bounds__(256) void gemm_split(
    const float* __restrict__ X,
    const __bf16* __restrict__ Agh, const __bf16* __restrict__ Agl,
    const __bf16* __restrict__ Bgh, const __bf16* __restrict__ Bgl,
    const float* __restrict__ bias,
    __bf16* __restrict__ Oh, __bf16* __restrict__ Ol,
    float* __restrict__ Of) {
  __shared__ __attribute__((aligned(16))) __bf16 Ah[128 * 32];
  __shared__ __attribute__((aligned(16))) __bf16 Al[128 * 32];
  __shared__ __attribute__((aligned(16))) __bf16 Bh[128 * 32];
  __shared__ __attribute__((aligned(16))) __bf16 Bl[128 * 32];

  const int t = threadIdx.x;
  const int wave = t >> 6;
  const int lane = t & 63;
  const int wm = wave & 1, wn = wave >> 1;
  const int tileM = blockIdx.y * 128;
  const int tileN = blockIdx.x * 128;

  f32x4 acc[4][4] = {};

  const int rS = lane >> 2;        // row within 16-row staging group
  const int cS = (lane & 3) * 8;   // k element offset within BK=32

  for (int kt = 0; kt < KDIM / 32; ++kt) {
    const int k0 = kt * 32;
    __syncthreads();
    // --- stage B^T tile (rows tileN..tileN+127, k0..k0+31), hi+lo
#pragma unroll
    for (int i = 0; i < 2; ++i) {
      const int rb = i * 64 + wave * 16;  // wave-uniform LDS row base
      const int gro = (tileN + rb + rS) * KDIM + k0 + cS;
      g2l16(Bgh + gro, &Bh[rb * 32]);
      g2l16(Bgl + gro, &Bl[rb * 32]);
    }
    if constexpr (MODE == 0) {
#pragma unroll
      for (int i = 0; i < 2; ++i) {
        const int rb = i * 64 + wave * 16;
        const int gro = (tileM + rb + rS) * KDIM + k0 + cS;
        g2l16(Agh + gro, &Ah[rb * 32]);
        g2l16(Agl + gro, &Al[rb * 32]);
      }
    } else {
      // inline fp32 -> bf16 hi/lo split of x during staging
#pragma unroll
      for (int i = 0; i < 4; ++i) {
        const int idx = i * 256 + t;
        const int row = idx >> 3;
        const int c4 = (idx & 7) * 4;
        const float4 v = *(const float4*)(X + (size_t)(tileM + row) * KDIM + k0 + c4);
        float vv[4] = {v.x, v.y, v.z, v.w};
        bf16x4 h, l;
#pragma unroll
        for (int j = 0; j < 4; ++j) {
          __bf16 hh = (__bf16)vv[j];
          h[j] = hh;
          l[j] = (__bf16)(vv[j] - (float)hh);
        }
        *(bf16x4*)(&Ah[row * 32 + c4]) = h;
        *(bf16x4*)(&Al[row * 32 + c4]) = l;
      }
    }
    __syncthreads();

    const int fr = lane & 15;
    const int fk = (lane >> 4) * 8;
    bf16x8 afh[4], afl[4], bfh[4], bfl[4];
#pragma unroll
    for (int mf = 0; mf < 4; ++mf) {
      const int r = wm * 64 + mf * 16 + fr;
      afh[mf] = *(const bf16x8*)(&Ah[r * 32 + fk]);
      afl[mf] = *(const bf16x8*)(&Al[r * 32 + fk]);
    }
#pragma unroll
    for (int nf = 0; nf < 4; ++nf) {
      const int r = wn * 64 + nf * 16 + fr;
      bfh[nf] = *(const bf16x8*)(&Bh[r * 32 + fk]);
      bfl[nf] = *(const bf16x8*)(&Bl[r * 32 + fk]);
    }
#pragma unroll
    for (int mf = 0; mf < 4; ++mf)
#pragma unroll
      for (int nf = 0; nf < 4; ++nf) {
        acc[mf][nf] = __builtin_amdgcn_mfma_f32_16x16x32_bf16(afh[mf], bfh[nf], acc[mf][nf], 0, 0, 0);
        acc[mf][nf] = __builtin_amdgcn_mfma_f32_16x16x32_bf16(afh[mf], bfl[nf], acc[mf][nf], 0, 0, 0);
        acc[mf][nf] = __builtin_amdgcn_mfma_f32_16x16x32_bf16(afl[mf], bfh[nf], acc[mf][nf], 0, 0, 0);
      }
  }

  // --- epilogue. C/D layout: col = lane&15, row = (lane>>4)*4 + reg
  const int er = (lane >> 4) * 4;
  const int ec = lane & 15;
#pragma unroll
  for (int nf = 0; nf < 4; ++nf) {
    const int col = tileN + wn * 64 + nf * 16 + ec;
    float bv = 0.0f;
    if constexpr (MODE == 1) bv = bias[col];
#pragma unroll
    for (int mf = 0; mf < 4; ++mf) {
#pragma unroll
      for (int r = 0; r < 4; ++r) {
        const int row = tileM + wm * 64 + mf * 16 + er + r;
        const size_t idx = (size_t)row * KDIM + col;
        float v = acc[mf][nf][r];
        if constexpr (MODE == 0) {
          __bf16 h = (__bf16)v;
          Oh[idx] = h;
          Ol[idx] = (__bf16)(v - (float)h);
        } else {
          Of[idx] = v + bv;
        }
      }
    }
  }
}

// ---------------------------------------------------------------------------
// Fused softmax + context GEMM.
// One block = 32 attn rows. 512 threads (8 waves). Per block:
//   1. read attn[32][1024] fp32 into registers (64 floats/thread, coalesced)
//   2. per-row max + expsum via 16-lane shuffle reductions (waves own 4 rows)
//   3. write normalized fp16 probs into XOR-swizzled LDS tile P[32][1024]
//   4. barrier-free K-loop: A-frags = ds_read_b128 from P (conflict-free via
//      swizzle), B-frags = direct global loads of L2-resident memT [d][m],
//      16x mfma_f32_16x16x32_f16 per K-step. No staging, no per-step barriers.
// Numerics identical to old softmax_k + gemm3: p = (fp16)(exp(v-m)*inv_sum),
// same K=32 ascending accumulation order.
__global__ __launch_bounds__(512, 4) void fused_softmax_ctx(
    const float* __restrict__ attn, const _Float16* __restrict__ memT,
    float* __restrict__ out) {
  __shared__ __attribute__((aligned(16))) _Float16 P[32 * 1024];  // 64 KB

  const int t = threadIdx.x;
  const int wave = t >> 6, lane = t & 63;
  const int riw = lane >> 4;       // row within wave's 4-row group
  const int cg = lane & 15;        // col group (16 threads per row)
  const int row = wave * 4 + riw;  // 0..31 (softmax phase row ownership)
  const size_t grow0 = (size_t)blockIdx.x * 32;

  // --- 1. load this row's 1024 attn values across its 16 threads (64 each)
  float4 v[16];
  {
    const float4* arow = (const float4*)(attn + (grow0 + row) * 1024);
#pragma unroll
    for (int j = 0; j < 16; ++j) v[j] = arow[cg + j * 16];
  }

  // --- 2a. row max (reduce over the 16-lane row group)
  float m = -1e30f;
#pragma unroll
  for (int j = 0; j < 16; ++j)
    m = fmaxf(m, fmaxf(fmaxf(v[j].x, v[j].y), fmaxf(v[j].z, v[j].w)));
#pragma unroll
  for (int off = 1; off < 16; off <<= 1) m = fmaxf(m, __shfl_xor(m, off));

  // --- 2b. exp in place + row sum
  float s = 0.f;
#pragma unroll
  for (int j = 0; j < 16; ++j) {
    v[j].x = expf(v[j].x - m);
    v[j].y = expf(v[j].y - m);
    v[j].z = expf(v[j].z - m);
    v[j].w = expf(v[j].w - m);
    s += (v[j].x + v[j].y) + (v[j].z + v[j].w);
  }
#pragma unroll
  for (int off = 1; off < 16; off <<= 1) s += __shfl_xor(s, off);
  const float inv = 1.0f / s;

  // --- 3. write normalized fp16 probs to LDS, XOR-swizzled by row
  {
    const int swz = (row & 7) << 4;
    char* rbase = (char*)P + row * 2048;
#pragma unroll
    for (int j = 0; j < 16; ++j) {
      half4v o;
      o[0] = (_Float16)(v[j].x * inv);
      o[1] = (_Float16)(v[j].y * inv);
      o[2] = (_Float16)(v[j].z * inv);
      o[3] = (_Float16)(v[j].w * inv);
      const int byteoff = (cg * 8 + j * 128) ^ swz;   // 8B-aligned, bijective
      *(half4v*)(rbase + byteoff) = o;
    }
  }
  __syncthreads();

  // --- 4. context GEMM: out[32 rows][wave's 128 cols] += P @ memT^T
  f32x4 acc[2][8] = {};
  const int colbase = wave * 128;
  const int fr = lane & 15;
  const int fko = (lane >> 4) * 8;   // k element offset within 32

  for (int kt = 0; kt < 32; ++kt) {
    const int k0 = kt * 32;
    half8 b[8];
#pragma unroll
    for (int nf = 0; nf < 8; ++nf)
      b[nf] = *(const half8*)(memT + (size_t)(colbase + nf * 16 + fr) * 1024 + k0 + fko);
    half8 a[2];
#pragma unroll
    for (int mf = 0; mf < 2; ++mf) {
      const int ar = mf * 16 + fr;
      const int kbyte = ((k0 + fko) * 2) ^ ((ar & 7) << 4);
      a[mf] = *(const half8*)((const char*)P + ar * 2048 + kbyte);
    }
#pragma unroll
    for (int mf = 0; mf < 2; ++mf)
#pragma unroll
      for (int nf = 0; nf < 8; ++nf)
        acc[mf][nf] = __builtin_amdgcn_mfma_f32_16x16x32_f16(a[mf], b[nf], acc[mf][nf], 0, 0, 0);
  }

  // --- epilogue. C/D layout: col = lane&15, row = (lane>>4)*4 + reg
  const int er = (lane >> 4) * 4;
  const int ec = lane & 15;
#pragma unroll
  for (int mf = 0; mf < 2; ++mf)
#pragma unroll
    for (int nf = 0; nf < 8; ++nf) {
      const int col = colbase + nf * 16 + ec;
#pragma unroll
      for (int r = 0; r < 4; ++r)
        out[(grow0 + mf * 16 + er + r) * 1024 + col] = acc[mf][nf][r];
    }
}

// ---------------------------------------------------------------------------
extern "C" void kernel_launch(void* const* d_in, const int* in_sizes, int n_in,
                              void* d_out, int out_size, void* d_ws, size_t ws_size,
                              hipStream_t stream) {
  const float* x   = (const float*)d_in[0];   // [32768][1024]
  const float* W   = (const float*)d_in[1];   // [1024][1024]  (out=e, in=d)
  const float* b   = (const float*)d_in[2];   // [1024]
  const float* mem = (const float*)d_in[3];   // [1024][1024]  (m, e)
  float* out = (float*)d_out;

  char* ws = (char*)d_ws;
  const size_t MB = 1024 * 1024;
  float*    attn  = (float*)(ws);              // 128 MB
  __bf16*   Mh    = (__bf16*)(ws + 192 * MB);  // 2 MB
  __bf16*   Ml    = (__bf16*)(ws + 194 * MB);  // 2 MB
  __bf16*   Wth   = (__bf16*)(ws + 196 * MB);  // 2 MB
  __bf16*   Wtl   = (__bf16*)(ws + 198 * MB);  // 2 MB
  __bf16*   Ph    = (__bf16*)(ws + 200 * MB);  // 2 MB
  __bf16*   Pl    = (__bf16*)(ws + 202 * MB);  // 2 MB
  _Float16* memT  = (_Float16*)(ws + 204 * MB);// 2 MB
  float*    cvec  = (float*)(ws + 206 * MB);   // 4 KB

  // preps (all tiny)
  split_mem<<<4096, 256, 0, stream>>>(mem, Mh, Ml);
  transpose_split_W<<<dim3(32, 32), dim3(32, 8), 0, stream>>>(W, Wth, Wtl);
  transpose_mem<<<dim3(32, 32), dim3(32, 8), 0, stream>>>(mem, memT);
  bias_c<<<256, 256, 0, stream>>>(b, mem, cvec);

  // P = mem @ W  (P[m][d] = sum_e mem[m][e] W[e][d]); split-bf16, out split bf16
  gemm_split<0><<<dim3(8, 8), 256, 0, stream>>>(
      nullptr, Mh, Ml, Wth, Wtl, nullptr, Ph, Pl, nullptr);

  // attn = x @ P^T + c  (split-bf16 via inline x split; fp32 logits)
  gemm_split<1><<<dim3(8, 256), 256, 0, stream>>>(
      x, nullptr, nullptr, Ph, Pl, cvec, nullptr, nullptr, attn);

  // fused softmax + context = probs @ mem  (fp16 single product via memT)
  fused_softmax_ctx<<<1024, 512, 0, stream>>>(attn, memT, out);
}